// Round 7
// baseline (768.125 us; speedup 1.0000x reference)
//
#include <hip/hip_runtime.h>
#include <stdint.h>

#define TB     400
#define OUTROW 160000   // T * 2F
#define NTHR   512
#define GRID   256      // (dir 2) x (seq 128), one block per sequence per direction

typedef _Float16 half2_t __attribute__((ext_vector_type(2)));

#if defined(__has_builtin)
#  if __has_builtin(__builtin_amdgcn_fdot2)
#    define HAVE_FDOT2 1
#  endif
#endif

__device__ __forceinline__ float sigf(float x){ return 1.0f/(1.0f+__expf(-x)); }
__device__ __forceinline__ float tanhf_(float x){ float e=__expf(2.0f*x); return 1.0f - 2.0f/(e+1.0f); }
__device__ __forceinline__ uint32_t pkh(float a, float b){
  half2_t h; h.x = (_Float16)a; h.y = (_Float16)b;
  return __builtin_bit_cast(uint32_t, h);
}
__device__ __forceinline__ float dot2f(uint32_t w, uint32_t x, float acc){
#ifdef HAVE_FDOT2
  return __builtin_amdgcn_fdot2(__builtin_bit_cast(half2_t, w),
                                __builtin_bit_cast(half2_t, x), acc, false);
#else
  half2_t a = __builtin_bit_cast(half2_t, w), b = __builtin_bit_cast(half2_t, x);
  return acc + (float)a.x*(float)b.x + (float)a.y*(float)b.y;
#endif
}

// Gates: K = 304 elems (x 0..99, m 100..299), padded to 320 = 160 pairs.
//   xp pair-slots: [0,50) x, [50,150) m, [150,160) pad (zeroed once; W pads are 0
//   but 0*garbage can be NaN in f16, so operand pads MUST be zeroed).
//   Thread (tid<400): sg = tid>>2 (cell unit), kq = tid&3 (k-quarter: pairs [40kq,40kq+40)).
//   Owns ALL 4 gate columns of sg -> cell update in-thread after 4-lane butterfly.
// Proj: K = 100 elems padded to 128 = 64 pairs; h2 slots [0,50) h, [50,64) pad.
//   Thread (tid<400): pcg = tid>>2 (col pair 2pcg,2pcg+1), kq = tid&3 (pairs [16kq,16kq+16)).

__global__ __launch_bounds__(NTHR, 2)
void lstm_v7(const float* __restrict__ z,
             const float* __restrict__ c0f, const float* __restrict__ m0f,
             const float* __restrict__ c0b, const float* __restrict__ m0b,
             const float* __restrict__ Wf, const float* __restrict__ bfv,
             const float* __restrict__ Pf,
             const float* __restrict__ Wb, const float* __restrict__ bbv,
             const float* __restrict__ Pb,
             float* __restrict__ out)
{
  __shared__ __align__(16) uint32_t xp[160];  // packed f16-pair activations [x | m | pad]
  __shared__ __align__(16) uint32_t h2[64];   // packed f16-pair h [h | pad]

  const int tid = threadIdx.x;
  const int dir = blockIdx.x >> 7;       // 0 fwd, 1 bwd
  const int seq = blockIdx.x & 127;

  const float* W   = dir ? Wb  : Wf;
  const float* bv  = dir ? bbv : bfv;
  const float* P   = dir ? Pb  : Pf;
  const float* c0v = dir ? c0b : c0f;
  const float* m0v = dir ? m0b : m0f;

  const int sg = tid >> 2;     // gates: cell unit / proj: column pair
  const int kq = tid & 3;      // k-quarter

  // ---- gates weights: wg[gate][j] quads; pairs [40kq,40kq+40) of column gate*100+sg ----
  uint4 wg[4][10];
  float bi = 0.f, bj = 0.f, bf1 = 0.f, bo = 0.f, cs = 0.f;
  if (tid < 400) {
    #pragma unroll
    for (int gt = 0; gt < 4; ++gt) {
      const int col = gt*100 + sg;
      #pragma unroll
      for (int j = 0; j < 10; ++j) {
        float f[8];
        #pragma unroll
        for (int p = 0; p < 4; ++p) {
          int pr = 40*kq + 4*j + p;         // pair index
          int k0 = 2*pr;
          f[2*p]   = (k0   < 300) ? W[(size_t)k0*400 + col] : 0.f;
          f[2*p+1] = (k0+1 < 300) ? W[(size_t)(k0+1)*400 + col] : 0.f;
        }
        wg[gt][j] = make_uint4(pkh(f[0],f[1]), pkh(f[2],f[3]), pkh(f[4],f[5]), pkh(f[6],f[7]));
      }
    }
    bi  = bv[sg];  bj = bv[100+sg];  bf1 = bv[200+sg] + 1.0f;  bo = bv[300+sg];
    cs  = c0v[(size_t)seq*100 + sg];          // replicated across the 4 kq lanes
  }

  // ---- proj weights: pg[cl][j] quads; pairs [16kq,16kq+16) of columns 2sg, 2sg+1 ----
  uint4 pg[2][4];
  if (tid < 400) {
    #pragma unroll
    for (int cl = 0; cl < 2; ++cl) {
      const int pc = 2*sg + cl;
      #pragma unroll
      for (int j = 0; j < 4; ++j) {
        float f[8];
        #pragma unroll
        for (int p = 0; p < 4; ++p) {
          int pr = 16*kq + 4*j + p;
          int k0 = 2*pr;
          f[2*p]   = (k0   < 100) ? P[(size_t)k0*200 + pc] : 0.f;
          f[2*p+1] = (k0+1 < 100) ? P[(size_t)(k0+1)*200 + pc] : 0.f;
        }
        pg[cl][j] = make_uint4(pkh(f[0],f[1]), pkh(f[2],f[3]), pkh(f[4],f[5]), pkh(f[6],f[7]));
      }
    }
  }

  // ---- init xp (x(t0), m0, pads), h2 pads ----
  if (tid < 50) {
    const float* zz = z + (size_t)seq*40000 + (size_t)(dir ? TB-1 : 0)*100;
    xp[tid] = pkh(zz[2*tid], zz[2*tid+1]);
  } else if (tid >= 64 && tid < 164) {
    int j = tid - 64;
    const float* mm = m0v + (size_t)seq*200;
    xp[50 + j] = pkh(mm[2*j], mm[2*j+1]);
  } else if (tid >= 192 && tid < 202) {
    xp[150 + (tid - 192)] = 0u;                    // gates K pad
  } else if (tid >= 256 && tid < 270) {
    h2[50 + (tid - 256)] = 0u;                     // proj K pad
  }
  __syncthreads();

  for (int t = 0; t < TB; ++t) {
    const int tt = dir ? (TB-1-t) : t;

    // x(t+1) prefetch by threads 400..499 (idle in gates; packed during proj phase)
    float xpre = 0.f;
    if (tid >= 400 && tid < 500 && t+1 < TB) {
      int ttn = dir ? (TB-2-t) : (t+1);
      xpre = z[(size_t)seq*40000 + (size_t)ttn*100 + (tid - 400)];
    }

    // (1) gates quarter-K dot for 4 gate columns + butterfly + in-thread cell update
    if (tid < 400) {
      float ai = 0.f, aj = 0.f, af = 0.f, ao = 0.f;
      #pragma unroll
      for (int j = 0; j < 10; ++j) {
        uint4 xv = *(const uint4*)(xp + 40*kq + 4*j);
        ai = dot2f(wg[0][j].x, xv.x, ai); ai = dot2f(wg[0][j].y, xv.y, ai);
        ai = dot2f(wg[0][j].z, xv.z, ai); ai = dot2f(wg[0][j].w, xv.w, ai);
        aj = dot2f(wg[1][j].x, xv.x, aj); aj = dot2f(wg[1][j].y, xv.y, aj);
        aj = dot2f(wg[1][j].z, xv.z, aj); aj = dot2f(wg[1][j].w, xv.w, aj);
        af = dot2f(wg[2][j].x, xv.x, af); af = dot2f(wg[2][j].y, xv.y, af);
        af = dot2f(wg[2][j].z, xv.z, af); af = dot2f(wg[2][j].w, xv.w, af);
        ao = dot2f(wg[3][j].x, xv.x, ao); ao = dot2f(wg[3][j].y, xv.y, ao);
        ao = dot2f(wg[3][j].z, xv.z, ao); ao = dot2f(wg[3][j].w, xv.w, ao);
      }
      // 4-lane butterfly: all kq lanes get full sums (cell replicated per lane)
      ai += __shfl_xor(ai, 1); ai += __shfl_xor(ai, 2);
      aj += __shfl_xor(aj, 1); aj += __shfl_xor(aj, 2);
      af += __shfl_xor(af, 1); af += __shfl_xor(af, 2);
      ao += __shfl_xor(ao, 1); ao += __shfl_xor(ao, 2);
      float iv = sigf(ai + bi);
      float jv = tanhf_(aj + bj);
      float fv = sigf(af + bf1);
      float ov = sigf(ao + bo);
      float cc = fv*cs + iv*jv;
      cs = cc;
      float h = ov*tanhf_(cc);
      float hn = __shfl_xor(h, 4);                 // h of sg^1 (same kq)
      if (kq == 0 && (sg & 1) == 0) h2[sg >> 1] = pkh(h, hn);
    }
    __syncthreads();                               // C: h2 ready

    // (2) projection quarter-K dot for column pair + butterfly + out + m-pack
    if (tid < 400) {
      float p0 = 0.f, p1 = 0.f;
      #pragma unroll
      for (int j = 0; j < 4; ++j) {
        uint4 hv = *(const uint4*)(h2 + 16*kq + 4*j);
        p0 = dot2f(pg[0][j].x, hv.x, p0); p0 = dot2f(pg[0][j].y, hv.y, p0);
        p0 = dot2f(pg[0][j].z, hv.z, p0); p0 = dot2f(pg[0][j].w, hv.w, p0);
        p1 = dot2f(pg[1][j].x, hv.x, p1); p1 = dot2f(pg[1][j].y, hv.y, p1);
        p1 = dot2f(pg[1][j].z, hv.z, p1); p1 = dot2f(pg[1][j].w, hv.w, p1);
      }
      p0 += __shfl_xor(p0, 1); p0 += __shfl_xor(p0, 2);
      p1 += __shfl_xor(p1, 1); p1 += __shfl_xor(p1, 2);
      float* ob = out + (size_t)seq*OUTROW + (size_t)tt*400 + dir*200;
      if (kq == 0) __builtin_nontemporal_store(p0, ob + 2*sg);
      if (kq == 1) __builtin_nontemporal_store(p1, ob + 2*sg + 1);
      if (kq == 2) xp[50 + sg] = pkh(p0, p1);      // m-pack: both cols in-thread
    }
    // (3) pack x(t+1)
    if (tid >= 400 && tid < 500 && t+1 < TB) {
      float xn = __shfl_xor(xpre, 1);
      if (((tid - 400) & 1) == 0) xp[(tid - 400) >> 1] = pkh(xpre, xn);
    }
    __syncthreads();                               // A: xp ready for next step
  }
}

extern "C" void kernel_launch(void* const* d_in, const int* in_sizes, int n_in,
                              void* d_out, int out_size, void* d_ws, size_t ws_size,
                              hipStream_t stream) {
  (void)in_sizes; (void)n_in; (void)out_size; (void)d_ws; (void)ws_size;
  lstm_v7<<<GRID, NTHR, 0, stream>>>((const float*)d_in[0],
      (const float*)d_in[1], (const float*)d_in[2],
      (const float*)d_in[3], (const float*)d_in[4],
      (const float*)d_in[5], (const float*)d_in[6], (const float*)d_in[7],
      (const float*)d_in[8], (const float*)d_in[9], (const float*)d_in[10],
      (float*)d_out);
}